// Round 2
// baseline (206.374 us; speedup 1.0000x reference)
//
#include <hip/hip_runtime.h>

typedef unsigned short u16;
typedef __attribute__((ext_vector_type(8))) short bf16x8;
typedef __attribute__((ext_vector_type(4))) float f32x4;

#define B_   8
#define S_   2048
#define IN_  256
#define D_   1024
#define OUT_ 256
#define KC_  32          // flash k-chunks
#define RC_  64          // rows per chunk = S_/KC_

// ---- workspace offsets (bytes) ----
#define OFF_WIT   0UL          // 1024x256 bf16   = 512K
#define OFF_WOT   524288UL     // 256x1024 bf16   = 512K
#define OFF_H     1048576UL    // 16384x1024 bf16 = 32M
#define OFF_AMAT  34603008UL   // 1024x1024 f32   = 4M   (Wq @ Wk^T)
#define OFF_AWO   38797312UL   // 1024x256 f32    = 1M   (Wv @ Wo)
#define OFF_C     39845888UL   // 1024 f32        (Wk @ bq)
#define OFF_CVOP  39849984UL   // 16x256 f32      (bv@Wo partials)
#define OFF_CVO   39866368UL   // 256 f32
#define OFF_U     39870464UL   // 8x1024 f32
#define OFF_PART  39903232UL   // 256x1024 f32    = 1M
#define OFF_MSUM  40951808UL   // 256x2 f32

static __device__ __forceinline__ float bf2f(u16 u) {
    union { unsigned i; float f; } x; x.i = ((unsigned)u) << 16; return x.f;
}
static __device__ __forceinline__ u16 f2bf(float f) {
    union { float f; unsigned i; } x; x.f = f;
    unsigned r = x.i + 0x7FFFu + ((x.i >> 16) & 1u);
    return (u16)(r >> 16);
}
static __device__ __forceinline__ float2 bf2x2(int p) {
    union { unsigned i; float f; } a, b;
    a.i = ((unsigned)p) << 16;
    b.i = ((unsigned)p) & 0xFFFF0000u;
    float2 r; r.x = a.f; r.y = b.f; return r;
}

// ================= K1: weight prep (transposes, c = Wk@bq, cvo partials) =================
__global__ __launch_bounds__(256) void k1(const float* __restrict__ Wi, u16* __restrict__ WiT,
                                          const float* __restrict__ Wo, u16* __restrict__ WoT,
                                          const float* __restrict__ Wk, const float* __restrict__ bq,
                                          float* __restrict__ cvec,
                                          const float* __restrict__ bv, float* __restrict__ cvop) {
    __shared__ float t[64][65];
    const int blk = blockIdx.x, tid = threadIdx.x;
    if (blk < 64) {
        // WiT[n][k] = bf16(Wi[k][n]);  Wi is [256][1024]
        const int n0 = (blk & 15) * 64, k0 = (blk >> 4) * 64;
        const int cc = tid & 63, rr = tid >> 6;
#pragma unroll
        for (int p = 0; p < 16; ++p) { int r = p * 4 + rr; t[r][cc] = Wi[(k0 + r) * 1024 + n0 + cc]; }
        __syncthreads();
#pragma unroll
        for (int p = 0; p < 16; ++p) { int n = p * 4 + rr; WiT[(n0 + n) * 256 + k0 + cc] = f2bf(t[cc][n]); }
    } else if (blk < 128) {
        // WoT[o][e] = bf16(Wo[e][o]);  Wo is [1024][256]
        const int b2 = blk - 64;
        const int e0 = (b2 & 15) * 64, o0 = (b2 >> 4) * 64;
        const int cc = tid & 63, rr = tid >> 6;
#pragma unroll
        for (int p = 0; p < 16; ++p) { int r = p * 4 + rr; t[r][cc] = Wo[(e0 + r) * 256 + o0 + cc]; }
        __syncthreads();
#pragma unroll
        for (int p = 0; p < 16; ++p) { int o = p * 4 + rr; WoT[(o0 + o) * 1024 + e0 + cc] = f2bf(t[cc][o]); }
    } else if (blk < 192) {
        // cvec[d] = sum_e Wk[d][e] * bq[e]
        const int b2 = blk - 128;
        const int w = tid >> 6, l = tid & 63;
        const int dbase = b2 * 16 + w * 4;
        float4 qv[4];
#pragma unroll
        for (int p = 0; p < 4; ++p) qv[p] = *reinterpret_cast<const float4*>(&bq[p * 256 + l * 4]);
#pragma unroll
        for (int i = 0; i < 4; ++i) {
            const int d = dbase + i;
            const float* wr = &Wk[(size_t)d * 1024];
            float acc = 0.f;
#pragma unroll
            for (int p = 0; p < 4; ++p) {
                float4 wv = *reinterpret_cast<const float4*>(&wr[p * 256 + l * 4]);
                acc += wv.x * qv[p].x + wv.y * qv[p].y + wv.z * qv[p].z + wv.w * qv[p].w;
            }
#pragma unroll
            for (int s = 32; s > 0; s >>= 1) acc += __shfl_xor(acc, s);
            if (l == 0) cvec[d] = acc;
        }
    } else {
        // cvop[chunk][o] = sum_{e in chunk} bv[e]*Wo[e][o]
        const int b2 = blk - 192;
        const int e0 = b2 * 64;
        float acc = 0.f;
        for (int e = 0; e < 64; ++e) acc += bv[e0 + e] * Wo[(size_t)(e0 + e) * 256 + tid];
        cvop[b2 * 256 + tid] = acc;
    }
}

// ================= generic 128x128 NT MFMA GEMM tile =================
template<bool CONVB, bool BF16OUT>
static __device__ __forceinline__ void gemm128(
    const float* __restrict__ Af, int lda,
    const void* __restrict__ Bsrc, int ldb,
    int m0, int n0, int K,
    u16* lA, u16* lB,
    const float* __restrict__ bias,
    u16* __restrict__ outb, float* __restrict__ outf, int ldo)
{
    const int tid = threadIdx.x;
    const int l = tid & 63, w = tid >> 6;
    const int wm = w >> 1, wn = w & 1;
    const int q = l >> 4, r = l & 15;
    f32x4 acc[4][4];
#pragma unroll
    for (int mt = 0; mt < 4; ++mt)
#pragma unroll
        for (int nt = 0; nt < 4; ++nt) acc[mt][nt] = (f32x4){0.f, 0.f, 0.f, 0.f};

    const int KH = K >> 7;
    for (int kh = 0; kh < KH; ++kh) {
        if (kh) __syncthreads();
        // stage A (f32 -> bf16), swizzled
#pragma unroll
        for (int p = 0; p < 8; ++p) {
            int id = p * 256 + tid;
            int row = id >> 4, cb = id & 15;
            const float4* src = reinterpret_cast<const float4*>(&Af[(size_t)(m0 + row) * lda + kh * 128 + cb * 8]);
            float4 v0 = src[0], v1 = src[1];
            int4 pk;
            pk.x = (int)f2bf(v0.x) | ((int)f2bf(v0.y) << 16);
            pk.y = (int)f2bf(v0.z) | ((int)f2bf(v0.w) << 16);
            pk.z = (int)f2bf(v1.x) | ((int)f2bf(v1.y) << 16);
            pk.w = (int)f2bf(v1.z) | ((int)f2bf(v1.w) << 16);
            *reinterpret_cast<int4*>(&lA[row * 128 + ((cb ^ (row & 7)) << 3)]) = pk;
        }
        // stage B
#pragma unroll
        for (int p = 0; p < 8; ++p) {
            int id = p * 256 + tid;
            int row = id >> 4, cb = id & 15;
            int4 pk;
            if constexpr (CONVB) {
                const float* Bf = (const float*)Bsrc;
                const float4* src = reinterpret_cast<const float4*>(&Bf[(size_t)(n0 + row) * ldb + kh * 128 + cb * 8]);
                float4 v0 = src[0], v1 = src[1];
                pk.x = (int)f2bf(v0.x) | ((int)f2bf(v0.y) << 16);
                pk.y = (int)f2bf(v0.z) | ((int)f2bf(v0.w) << 16);
                pk.z = (int)f2bf(v1.x) | ((int)f2bf(v1.y) << 16);
                pk.w = (int)f2bf(v1.z) | ((int)f2bf(v1.w) << 16);
            } else {
                const u16* Bb = (const u16*)Bsrc;
                pk = *reinterpret_cast<const int4*>(&Bb[(size_t)(n0 + row) * ldb + kh * 128 + cb * 8]);
            }
            *reinterpret_cast<int4*>(&lB[row * 128 + ((cb ^ (row & 7)) << 3)]) = pk;
        }
        __syncthreads();
#pragma unroll
        for (int kk = 0; kk < 4; ++kk) {
            int cb = kk * 4 + q;
            bf16x8 af[4], bfr[4];
#pragma unroll
            for (int mt = 0; mt < 4; ++mt) {
                int row = wm * 64 + mt * 16 + r;
                af[mt] = *reinterpret_cast<const bf16x8*>(&lA[row * 128 + ((cb ^ (row & 7)) << 3)]);
            }
#pragma unroll
            for (int nt = 0; nt < 4; ++nt) {
                int row = wn * 64 + nt * 16 + r;
                bfr[nt] = *reinterpret_cast<const bf16x8*>(&lB[row * 128 + ((cb ^ (row & 7)) << 3)]);
            }
#pragma unroll
            for (int mt = 0; mt < 4; ++mt)
#pragma unroll
                for (int nt = 0; nt < 4; ++nt)
                    acc[mt][nt] = __builtin_amdgcn_mfma_f32_16x16x32_bf16(af[mt], bfr[nt], acc[mt][nt], 0, 0, 0);
        }
    }
    // epilogue.  C/D map: col=lane&15, row=(lane>>4)*4+j
#pragma unroll
    for (int nt = 0; nt < 4; ++nt) {
        int col = n0 + wn * 64 + nt * 16 + r;
        float bb = 0.f;
        if constexpr (BF16OUT) bb = bias[col];
#pragma unroll
        for (int mt = 0; mt < 4; ++mt) {
#pragma unroll
            for (int j = 0; j < 4; ++j) {
                int row = m0 + wm * 64 + mt * 16 + q * 4 + j;
                if constexpr (BF16OUT) outb[(size_t)row * ldo + col] = f2bf(acc[mt][nt][j] + bb);
                else                   outf[(size_t)row * ldo + col] = acc[mt][nt][j];
            }
        }
    }
}

// ================= K2: h-GEMM || A=Wq@Wk^T || Awo=Wv@Wo =================
__global__ __launch_bounds__(256) void k2(const float* __restrict__ x, const u16* __restrict__ WiT,
                                          const float* __restrict__ bi, u16* __restrict__ h,
                                          const float* __restrict__ Wq, const float* __restrict__ Wk,
                                          float* __restrict__ Amat,
                                          const float* __restrict__ Wv, const u16* __restrict__ WoT,
                                          float* __restrict__ Awo) {
    __shared__ u16 lds[2 * 128 * 128];
    u16* lA = lds;
    u16* lB = lds + 128 * 128;
    const int blk = blockIdx.x;
    if (blk < 1024) {
        int mt = blk >> 3, nt = blk & 7;
        gemm128<false, true>(x, IN_, WiT, IN_, mt * 128, nt * 128, IN_, lA, lB, bi, h, nullptr, D_);
    } else if (blk < 1088) {
        int t = blk - 1024;
        int mt = t >> 3, nt = t & 7;
        gemm128<true, false>(Wq, D_, Wk, D_, mt * 128, nt * 128, D_, lA, lB, nullptr, nullptr, Amat, D_);
    } else {
        int t = blk - 1088;
        int mt = t >> 1, nt = t & 1;
        gemm128<false, false>(Wv, D_, WoT, D_, mt * 128, nt * 128, D_, lA, lB, nullptr, nullptr, Awo, OUT_);
    }
}

// ================= K3: u[b] = h_last[b] @ Amat + c ; cvo finish =================
__global__ __launch_bounds__(256) void k3(const u16* __restrict__ h, const float* __restrict__ Amat,
                                          const float* __restrict__ cvec, float* __restrict__ u,
                                          const float* __restrict__ cvop, const float* __restrict__ bo,
                                          float* __restrict__ cvo) {
    const int blk = blockIdx.x, tid = threadIdx.x;
    if (blk < 128) {
        const int b = blk >> 4, dc = blk & 15;
        __shared__ float hl[1024];
        __shared__ float red[4][64];
        {
            const size_t hb = ((size_t)(b * S_ + S_ - 1)) * D_;
            int2 hv = *reinterpret_cast<const int2*>(&h[hb + tid * 4]);
            float2 p0 = bf2x2(hv.x), p1 = bf2x2(hv.y);
            hl[tid * 4 + 0] = p0.x; hl[tid * 4 + 1] = p0.y;
            hl[tid * 4 + 2] = p1.x; hl[tid * 4 + 3] = p1.y;
        }
        __syncthreads();
        const int dl = tid & 63, qd = tid >> 6;
        const int d = dc * 64 + dl;
        float ac[8] = {0.f, 0.f, 0.f, 0.f, 0.f, 0.f, 0.f, 0.f};
        for (int dp = qd * 256; dp < qd * 256 + 256; dp += 8) {
            float hh[8];
#pragma unroll
            for (int i = 0; i < 8; ++i) hh[i] = hl[dp + i];
#pragma unroll
            for (int i = 0; i < 8; ++i) ac[i] += hh[i] * Amat[(size_t)(dp + i) * D_ + d];
        }
        float acc = ((ac[0] + ac[1]) + (ac[2] + ac[3])) + ((ac[4] + ac[5]) + (ac[6] + ac[7]));
        red[qd][dl] = acc;
        __syncthreads();
        if (qd == 0) {
            float s = red[0][dl] + red[1][dl] + red[2][dl] + red[3][dl];
            u[b * D_ + d] = s + cvec[d];
        }
    } else {
        // cvo[o] = sum_chunks cvop + bo
        float s = bo[tid];
#pragma unroll
        for (int j = 0; j < 16; ++j) s += cvop[j * 256 + tid];
        cvo[tid] = s;
    }
}

// ================= K4: flash partial per (kc, b) over 64 rows =================
__global__ __launch_bounds__(256) void k4(const u16* __restrict__ h, const float* __restrict__ u,
                                          float* __restrict__ part, float* __restrict__ msum) {
    const int kc = blockIdx.x, b = blockIdx.y;
    const int tid = threadIdx.x, w = tid >> 6, l = tid & 63;
    __shared__ float sNp[RC_];
    // u slice in regs: lane l owns u[l*16 .. l*16+15]
    float uv[16];
    {
        const float* ub = &u[b * D_ + l * 16];
#pragma unroll
        for (int p = 0; p < 4; ++p) {
            float4 v = *reinterpret_cast<const float4*>(&ub[p * 4]);
            uv[p * 4 + 0] = v.x; uv[p * 4 + 1] = v.y; uv[p * 4 + 2] = v.z; uv[p * 4 + 3] = v.w;
        }
    }
    const size_t base = ((size_t)(b * S_) + kc * RC_) * D_;
    // phase A: scores (each wave: 16 rows)
    for (int rr = 0; rr < 16; ++rr) {
        const int row = w * 16 + rr;
        const u16* hr = &h[base + (size_t)row * D_ + l * 16];
        int4 q0 = *reinterpret_cast<const int4*>(&hr[0]);
        int4 q1 = *reinterpret_cast<const int4*>(&hr[8]);
        float2 a0 = bf2x2(q0.x), a1 = bf2x2(q0.y), a2 = bf2x2(q0.z), a3 = bf2x2(q0.w);
        float2 c0 = bf2x2(q1.x), c1 = bf2x2(q1.y), c2 = bf2x2(q1.z), c3 = bf2x2(q1.w);
        float acc = a0.x * uv[0] + a0.y * uv[1] + a1.x * uv[2] + a1.y * uv[3]
                  + a2.x * uv[4] + a2.y * uv[5] + a3.x * uv[6] + a3.y * uv[7]
                  + c0.x * uv[8] + c0.y * uv[9] + c1.x * uv[10] + c1.y * uv[11]
                  + c2.x * uv[12] + c2.y * uv[13] + c3.x * uv[14] + c3.y * uv[15];
#pragma unroll
        for (int s = 32; s > 0; s >>= 1) acc += __shfl_xor(acc, s);
        if (l == 0) sNp[row] = acc * 0.03125f;   // 1/sqrt(1024)
    }
    __syncthreads();
    // phase B: local softmax (each wave redundantly reduces its own copy of all 64 scores)
    float sv = sNp[l];
    float mx = sv;
#pragma unroll
    for (int s = 32; s > 0; s >>= 1) mx = fmaxf(mx, __shfl_xor(mx, s));
    float p = __expf(sv - mx);
    float sum = p;
#pragma unroll
    for (int s = 32; s > 0; s >>= 1) sum += __shfl_xor(sum, s);
    __syncthreads();   // all reads of sNp done before overwrite
    if (w == 0) sNp[l] = p;
    if (tid == 0) { msum[(kc * 8 + b) * 2] = mx; msum[(kc * 8 + b) * 2 + 1] = sum; }
    __syncthreads();
    // phase C: partial[d] = sum_k p_k h[k][d]
    const int d0 = tid * 4;
    float a0 = 0.f, a1 = 0.f, a2 = 0.f, a3 = 0.f;
    for (int k = 0; k < RC_; ++k) {
        float pk = sNp[k];
        int2 hv = *reinterpret_cast<const int2*>(&h[base + (size_t)k * D_ + d0]);
        float2 x0 = bf2x2(hv.x), x1 = bf2x2(hv.y);
        a0 += pk * x0.x; a1 += pk * x0.y; a2 += pk * x1.x; a3 += pk * x1.y;
    }
    float4 st = {a0, a1, a2, a3};
    *reinterpret_cast<float4*>(&part[((size_t)(kc * 8 + b)) * D_ + d0]) = st;
}

// ================= K5: combine partials -> hbar -> out = hbar@Awo + cvo =================
__global__ __launch_bounds__(256) void k5(const float* __restrict__ part, const float* __restrict__ msum,
                                          const float* __restrict__ Awo, const float* __restrict__ cvo,
                                          float* __restrict__ out) {
    const int b = blockIdx.x, tid = threadIdx.x, w = tid >> 6, l = tid & 63;
    __shared__ float hbar[1024];
    __shared__ float red[4][256];
    float m[KC_], sm[KC_];
    float M = -1e30f;
#pragma unroll
    for (int c = 0; c < KC_; ++c) {
        m[c] = msum[(c * 8 + b) * 2];
        sm[c] = msum[(c * 8 + b) * 2 + 1];
        M = fmaxf(M, m[c]);
    }
    float denom = 0.f;
    float wgt[KC_];
#pragma unroll
    for (int c = 0; c < KC_; ++c) { wgt[c] = __expf(m[c] - M); denom += wgt[c] * sm[c]; }
    const float inv = 1.f / denom;
    float h0 = 0.f, h1 = 0.f, h2 = 0.f, h3 = 0.f;
#pragma unroll
    for (int c = 0; c < KC_; ++c) {
        float4 pv = *reinterpret_cast<const float4*>(&part[((size_t)(c * 8 + b)) * D_ + tid * 4]);
        h0 += wgt[c] * pv.x; h1 += wgt[c] * pv.y; h2 += wgt[c] * pv.z; h3 += wgt[c] * pv.w;
    }
    hbar[tid * 4 + 0] = h0 * inv; hbar[tid * 4 + 1] = h1 * inv;
    hbar[tid * 4 + 2] = h2 * inv; hbar[tid * 4 + 3] = h3 * inv;
    __syncthreads();
    // out: wave w covers d in [w*256, w*256+256); lane owns o = l*4..l*4+3
    float o0 = 0.f, o1 = 0.f, o2 = 0.f, o3 = 0.f;
    for (int d = w * 256; d < w * 256 + 256; d += 4) {
        float4 hv = *reinterpret_cast<const float4*>(&hbar[d]);
#pragma unroll
        for (int j = 0; j < 4; ++j) {
            float hj = (j == 0) ? hv.x : (j == 1) ? hv.y : (j == 2) ? hv.z : hv.w;
            float4 av = *reinterpret_cast<const float4*>(&Awo[(size_t)(d + j) * OUT_ + l * 4]);
            o0 += hj * av.x; o1 += hj * av.y; o2 += hj * av.z; o3 += hj * av.w;
        }
    }
    red[w][l * 4 + 0] = o0; red[w][l * 4 + 1] = o1;
    red[w][l * 4 + 2] = o2; red[w][l * 4 + 3] = o3;
    __syncthreads();
    float r = red[0][tid] + red[1][tid] + red[2][tid] + red[3][tid] + cvo[tid];
    out[b * OUT_ + tid] = r;
}

extern "C" void kernel_launch(void* const* d_in, const int* in_sizes, int n_in,
                              void* d_out, int out_size, void* d_ws, size_t ws_size,
                              hipStream_t stream) {
    const float* x  = (const float*)d_in[0];
    const float* Wi = (const float*)d_in[1];
    const float* bi = (const float*)d_in[2];
    const float* Wq = (const float*)d_in[3];
    const float* bq = (const float*)d_in[4];
    const float* Wk = (const float*)d_in[5];
    // d_in[6] = bk : unused (softmax shift invariance)
    const float* Wv = (const float*)d_in[7];
    const float* bv = (const float*)d_in[8];
    const float* Wo = (const float*)d_in[9];
    const float* bo = (const float*)d_in[10];
    float* out = (float*)d_out;

    char* ws = (char*)d_ws;
    u16*   WiT  = (u16*)  (ws + OFF_WIT);
    u16*   WoT  = (u16*)  (ws + OFF_WOT);
    u16*   h    = (u16*)  (ws + OFF_H);
    float* Amat = (float*)(ws + OFF_AMAT);
    float* Awo  = (float*)(ws + OFF_AWO);
    float* cvec = (float*)(ws + OFF_C);
    float* cvop = (float*)(ws + OFF_CVOP);
    float* cvo  = (float*)(ws + OFF_CVO);
    float* uvec = (float*)(ws + OFF_U);
    float* part = (float*)(ws + OFF_PART);
    float* msum = (float*)(ws + OFF_MSUM);

    k1<<<208,        256, 0, stream>>>(Wi, WiT, Wo, WoT, Wk, bq, cvec, bv, cvop);
    k2<<<1104,       256, 0, stream>>>(x, WiT, bi, h, Wq, Wk, Amat, Wv, WoT, Awo);
    k3<<<129,        256, 0, stream>>>(h, Amat, cvec, uvec, cvop, bo, cvo);
    k4<<<dim3(32,8), 256, 0, stream>>>(h, uvec, part, msum);
    k5<<<8,          256, 0, stream>>>(part, msum, Awo, cvo, out);
}